// Round 11
// baseline (176.408 us; speedup 1.0000x reference)
//
#include <hip/hip_runtime.h>
#include <cstdint>
#include <cstddef>

// ---------------------------------------------------------------------------
// QLSTM on MI355X.
//
// Math: qlayer(ang)[w] = prod_{v in S_w} cos(ang_v), S_w from the GF(2)-linear
// CNOT-ring permutation (DEPTH=2, 8 qubits, wire0=MSB). Verified 3x.
// Packed little-endian byte-per-wire: 0x55AAD5EAF5FAFDAB.
//
// R3 72us (libm) -> R4 47.5 (native trans) -> R6 46.2 (DPP, null) ->
// R8 ~33us inferred (reg-chunked xp preload + permlane32 + no LDS in loop).
// R8 learned: scan is a pure latency chain (~620cy/step); top-5 is now the
// harness's 256MiB ws re-poison (43us, uncontrollable). R11: interleave TWO
// independent rows per lane (dual chains per wave) -> ILP hides dependent
// latency; wall-clock per row-step ~halves. Grid 32 blocks, dup state.
// ---------------------------------------------------------------------------

constexpr int SEQ    = 128;
constexpr int NBATCH = 512;
constexpr int INDIM  = 64;
constexpr int FANIN  = 72;   // INPUT_DIM + HIDDEN_DIM
constexpr long OUT_HX = (long)SEQ * NBATCH * 8;
constexpr long OUT_CX = OUT_HX + (long)NBATCH * 8;

#define SWZ(v, imm) __int_as_float(__builtin_amdgcn_ds_swizzle(__float_as_int(v), (imm)))

__device__ __forceinline__ float fast_cos(float ang) {
    // cos(ang) = v_cos(fract(ang / 2pi)); v_cos takes revolutions in [0,1).
    const float rev = ang * 0.15915494309189535f;
    return __builtin_amdgcn_cosf(__builtin_amdgcn_fractf(rev));
}

// DPP helpers (proven R6-R10). result[l] = x[l ^ XORMASK] per ctrl:
//   0xB1 quad_perm=^1   0x4E quad_perm=^2   0x1B quad_perm=^3
//   0x141 ROW_HALF_MIRROR=^7   0x140 ROW_MIRROR=^15   0x128 ROW_ROR:8=^8
template <int CTRL> __device__ __forceinline__ float DPPF(float x) {
    return __int_as_float(__builtin_amdgcn_update_dpp(
        0, __float_as_int(x), CTRL, 0xF, 0xF, false));
}

// lane^32 exchange via v_permlane32_swap (proven R10 run: passed).
__device__ __forceinline__ float xlane32(float x, bool hiHalf) {
#if __has_builtin(__builtin_amdgcn_permlane32_swap)
    typedef unsigned uint2v __attribute__((ext_vector_type(2)));
    uint2v r = __builtin_amdgcn_permlane32_swap(
        __float_as_uint(x), __float_as_uint(x), false, false);
    return __uint_as_float(hiHalf ? r[0] : r[1]);
#else
    (void)hiHalf;
    return __shfl_xor(x, 32, 64);
#endif
}

// ---------------------------------------------------------------------------
// Kernel A: xp[t*512+b][g*8+w] = sum_k x[t,b,k]*W_g[w,k] + b_g[w] + th_g[w]
// (unchanged since R4; never in top-5)
// ---------------------------------------------------------------------------
__global__ __launch_bounds__(256) void xproj_kernel(
    const float* __restrict__ x,
    const float* __restrict__ Wf, const float* __restrict__ bf, const float* __restrict__ thf,
    const float* __restrict__ Wi, const float* __restrict__ bi, const float* __restrict__ thi,
    const float* __restrict__ Wu, const float* __restrict__ bu, const float* __restrict__ thu,
    const float* __restrict__ Wo, const float* __restrict__ bo, const float* __restrict__ tho,
    float* __restrict__ xp)
{
    __shared__ float lx[128 * 68];
    __shared__ float lbias[32];
    const int tid = threadIdx.x;
    const long rowBase = (long)blockIdx.x * 128;

    if (tid < 32) {
        const int g = tid >> 3, w = tid & 7;
        const float* bg = (g == 0) ? bf : (g == 1) ? bi : (g == 2) ? bu : bo;
        const float* tg = (g == 0) ? thf : (g == 1) ? thi : (g == 2) ? thu : tho;
        lbias[tid] = bg[w] + tg[w];
    }

    const float4* xin = reinterpret_cast<const float4*>(x + rowBase * INDIM);
#pragma unroll
    for (int i = 0; i < 8; ++i) {
        const int f   = i * 256 + tid;
        const int row = f >> 4;
        const int kq  = f & 15;
        *reinterpret_cast<float4*>(&lx[row * 68 + kq * 4]) = xin[f];
    }
    __syncthreads();

    const int og = tid & 3;
    const int q  = tid >> 2;
    const float* Wg = (og == 0) ? Wf : (og == 1) ? Wi : (og == 2) ? Wu : Wo;

    float acc[2][8];
#pragma unroll
    for (int r = 0; r < 2; ++r)
#pragma unroll
        for (int j = 0; j < 8; ++j) acc[r][j] = 0.f;

#pragma unroll
    for (int k4 = 0; k4 < 16; ++k4) {
        const float4 x0 = *reinterpret_cast<const float4*>(&lx[q * 68 + k4 * 4]);
        const float4 x1 = *reinterpret_cast<const float4*>(&lx[(q + 64) * 68 + k4 * 4]);
#pragma unroll
        for (int j = 0; j < 8; ++j) {
            const float4 wv = *reinterpret_cast<const float4*>(Wg + j * FANIN + k4 * 4);
            acc[0][j] = fmaf(x0.x, wv.x, acc[0][j]);
            acc[0][j] = fmaf(x0.y, wv.y, acc[0][j]);
            acc[0][j] = fmaf(x0.z, wv.z, acc[0][j]);
            acc[0][j] = fmaf(x0.w, wv.w, acc[0][j]);
            acc[1][j] = fmaf(x1.x, wv.x, acc[1][j]);
            acc[1][j] = fmaf(x1.y, wv.y, acc[1][j]);
            acc[1][j] = fmaf(x1.z, wv.z, acc[1][j]);
            acc[1][j] = fmaf(x1.w, wv.w, acc[1][j]);
        }
    }

#pragma unroll
    for (int r = 0; r < 2; ++r) {
        float4 o0, o1;
        o0.x = acc[r][0] + lbias[og * 8 + 0];
        o0.y = acc[r][1] + lbias[og * 8 + 1];
        o0.z = acc[r][2] + lbias[og * 8 + 2];
        o0.w = acc[r][3] + lbias[og * 8 + 3];
        o1.x = acc[r][4] + lbias[og * 8 + 4];
        o1.y = acc[r][5] + lbias[og * 8 + 5];
        o1.z = acc[r][6] + lbias[og * 8 + 6];
        o1.w = acc[r][7] + lbias[og * 8 + 7];
        float* dst = xp + (rowBase + q + 64 * r) * 32 + og * 8;
        reinterpret_cast<float4*>(dst)[0] = o0;
        reinterpret_cast<float4*>(dst)[1] = o1;
    }
}

// ---------------------------------------------------------------------------
// One recurrence step for one row (R8's proven QSTEP as an inline function;
// two back-to-back calls on independent rows give the scheduler dual chains).
// ---------------------------------------------------------------------------
__device__ __forceinline__ void qstep(
    float xv, int t, int row, int w,
    const float whx[8], const bool pm[8],
    float ZL, float A, float B, bool gOdd, bool gHi, bool doOut,
    float& hh0, float& hh1, float& hh2, float& hh3,
    float& hh4, float& hh5, float& hh6, float& hh7,
    float& cxl, float* __restrict__ out)
{
    const float d0 = fmaf(hh0, whx[0], fmaf(hh1, whx[1], fmaf(hh2, whx[2], hh3 * whx[3])));
    const float d1 = fmaf(hh4, whx[4], fmaf(hh5, whx[5], fmaf(hh6, whx[6], hh7 * whx[7])));
    const float ang = xv + d0 + d1;

    const float c0 = fast_cos(ang);
    const float c1 = DPPF<0x4E>(c0);
    const float c2 = DPPF<0x141>(DPPF<0x1B>(c0));
    const float c3 = DPPF<0x141>(DPPF<0xB1>(c0));
    const float c4 = DPPF<0x128>(c0);
    const float c5 = DPPF<0x128>(DPPF<0x4E>(c0));
    const float c6 = DPPF<0x140>(DPPF<0x1B>(c0));
    const float c7 = DPPF<0x140>(DPPF<0xB1>(c0));

    const float z = (((pm[0] ? c0 : 1.0f) * (pm[1] ? c1 : 1.0f))
                   * ((pm[2] ? c2 : 1.0f) * (pm[3] ? c3 : 1.0f)))
                  * (((pm[4] ? c4 : 1.0f) * (pm[5] ? c5 : 1.0f))
                   * ((pm[6] ? c6 : 1.0f) * (pm[7] ? c7 : 1.0f)));

    const float e   = __expf(z * ZL);
    const float act = fmaf(A, __builtin_amdgcn_rcpf(1.0f + e), B);

    const float a01 = DPPF<0xB1>(act);
    const float ae  = gOdd ? a01 : act;
    const float ao  = gOdd ? act : a01;
    const float be  = xlane32(ae, gHi);
    const float bo  = xlane32(ao, gHi);
    const float fg  = gHi ? be : ae;
    const float ig  = gHi ? bo : ao;
    const float ug  = gHi ? ae : be;
    const float og  = gHi ? ao : bo;

    const float ncx = fmaf(fg, cxl, ig * ug);
    const float et  = __expf(-2.0f * ncx);
    const float tc  = fmaf(2.0f, __builtin_amdgcn_rcpf(1.0f + et), -1.0f);
    const float nhx = og * tc;
    cxl = ncx;

    if (doOut) out[((long)t * NBATCH + row) * 8 + w] = nhx;

    hh0 = nhx;
    hh1 = DPPF<0x4E>(nhx);
    hh2 = DPPF<0x141>(DPPF<0x1B>(nhx));
    hh3 = DPPF<0x141>(DPPF<0xB1>(nhx));
    hh4 = DPPF<0x128>(nhx);
    hh5 = DPPF<0x128>(DPPF<0x4E>(nhx));
    hh6 = DPPF<0x140>(DPPF<0x1B>(nhx));
    hh7 = DPPF<0x140>(DPPF<0xB1>(nhx));
}

// ---------------------------------------------------------------------------
// Kernel B (R11): lane = g0 | w<<1 | rsub<<4 | g1<<5; each lane carries TWO
// rows (rowL, rowH = rowL+256) with fully duplicated state -> dual
// independent dependency chains per wave. Grid = 32 blocks x 256 threads.
// xp preloaded in 8-step register chunks per row (double-buffered).
// ---------------------------------------------------------------------------
__global__ __launch_bounds__(256) void qlstm_scan_kernel(
    const float* __restrict__ xp,
    const float* __restrict__ Wf, const float* __restrict__ Wi,
    const float* __restrict__ Wu, const float* __restrict__ Wo,
    float* __restrict__ out)
{
    const int tid  = threadIdx.x;
    const int lane = tid & 63;
    const int wv   = tid >> 6;                          // wave 0..3
    const int g1   = (lane >> 5) & 1;
    const int g    = (lane & 1) | (g1 << 1);
    const int w    = (lane >> 1) & 7;
    const int rsub = (lane >> 4) & 1;
    const int rowL = (blockIdx.x << 3) + (wv << 1) + rsub;   // 0..255
    const int rowH = rowL + 256;                             // 256..511

    const float* Wg = (g == 0) ? Wf : (g == 1) ? Wi : (g == 2) ? Wu : Wo;

    float whx[8];
#pragma unroll
    for (int d = 0; d < 8; ++d) whx[d] = Wg[w * FANIN + 64 + (w ^ d)];

    const unsigned mask = (unsigned)((0x55AAD5EAF5FAFDABull >> (w * 8)) & 0xFFull);
    bool pm[8];
#pragma unroll
    for (int d = 0; d < 8; ++d) pm[d] = ((mask >> (w ^ d)) & 1u) != 0u;

    const bool  isU   = (g == 2);
    const float ZL    = isU ? -2.0f : -1.0f;
    const float A     = isU ?  2.0f :  1.0f;
    const float B     = isU ? -1.0f :  0.0f;
    const bool  gOdd  = (lane & 1) != 0;
    const bool  gHi   = g1 != 0;
    const bool  doOut = (lane & 0x21) == 0;

    const int col = g * 8 + w;

    float hL0=0.f,hL1=0.f,hL2=0.f,hL3=0.f,hL4=0.f,hL5=0.f,hL6=0.f,hL7=0.f,cxL=0.f;
    float hH0=0.f,hH1=0.f,hH2=0.f,hH3=0.f,hH4=0.f,hH5=0.f,hH6=0.f,hH7=0.f,cxH=0.f;

    // 8-step register chunks per row, double-buffered (static indices).
    float xvaL[8], xvbL[8], xvaH[8], xvbH[8];
#pragma unroll
    for (int j = 0; j < 8; ++j) {
        xvaL[j] = xp[((long)j * NBATCH + rowL) * 32 + col];
        xvaH[j] = xp[((long)j * NBATCH + rowH) * 32 + col];
    }

#pragma unroll 1
    for (int ck = 0; ck < 16; ++ck) {
        const int t0 = ck * 8;
        if (ck < 15) {
#pragma unroll
            for (int j = 0; j < 8; ++j) {
                xvbL[j] = xp[((long)(t0 + 8 + j) * NBATCH + rowL) * 32 + col];
                xvbH[j] = xp[((long)(t0 + 8 + j) * NBATCH + rowH) * 32 + col];
            }
        }
#pragma unroll
        for (int j = 0; j < 8; ++j) {
            qstep(xvaL[j], t0 + j, rowL, w, whx, pm, ZL, A, B, gOdd, gHi, doOut,
                  hL0, hL1, hL2, hL3, hL4, hL5, hL6, hL7, cxL, out);
            qstep(xvaH[j], t0 + j, rowH, w, whx, pm, ZL, A, B, gOdd, gHi, doOut,
                  hH0, hH1, hH2, hH3, hH4, hH5, hH6, hH7, cxH, out);
        }
#pragma unroll
        for (int j = 0; j < 8; ++j) { xvaL[j] = xvbL[j]; xvaH[j] = xvbH[j]; }
    }

    if (doOut) {
        out[OUT_HX + (long)rowL * 8 + w] = hL0;
        out[OUT_CX + (long)rowL * 8 + w] = cxL;
        out[OUT_HX + (long)rowH * 8 + w] = hH0;
        out[OUT_CX + (long)rowH * 8 + w] = cxH;
    }
}

// ---------------------------------------------------------------------------
// FUSED fallback (ws too small): R4's proven kernel, old 32-lane layout.
// ---------------------------------------------------------------------------
__global__ __launch_bounds__(256) void qlstm_scan_fused(
    const float* __restrict__ x,
    const float* __restrict__ Wf, const float* __restrict__ bf, const float* __restrict__ thf,
    const float* __restrict__ Wi, const float* __restrict__ bi, const float* __restrict__ thi,
    const float* __restrict__ Wu, const float* __restrict__ bu, const float* __restrict__ thu,
    const float* __restrict__ Wo, const float* __restrict__ bo, const float* __restrict__ tho,
    float* __restrict__ out)
{
    const int tid  = threadIdx.x;
    const int lane = tid & 31;
    const int row  = (blockIdx.x << 3) + (tid >> 5);
    const int g    = lane >> 3;
    const int w    = lane & 7;

    const float* Wg = (g == 0) ? Wf : (g == 1) ? Wi : (g == 2) ? Wu : Wo;
    const float* bg = (g == 0) ? bf : (g == 1) ? bi : (g == 2) ? bu : bo;
    const float* tg = (g == 0) ? thf : (g == 1) ? thi : (g == 2) ? thu : tho;

    float wh0, wh1, wh2, wh3, wh4, wh5, wh6, wh7;
    {
        const float4* p = reinterpret_cast<const float4*>(Wg + w * FANIN + 64);
        const float4 a = p[0], b4 = p[1];
        wh0 = a.x; wh1 = a.y; wh2 = a.z; wh3 = a.w;
        wh4 = b4.x; wh5 = b4.y; wh6 = b4.z; wh7 = b4.w;
    }
    const float bias = bg[w] + tg[w];
    float wx[64];
#pragma unroll
    for (int k4 = 0; k4 < 16; ++k4) {
        const float4 v = reinterpret_cast<const float4*>(Wg + w * FANIN)[k4];
        wx[4*k4+0] = v.x; wx[4*k4+1] = v.y; wx[4*k4+2] = v.z; wx[4*k4+3] = v.w;
    }

    const unsigned mask = (unsigned)((0x55AAD5EAF5FAFDABull >> (w * 8)) & 0xFFull);
    const bool  isU = (g == 2);
    const float ZL  = isU ? -2.0f : -1.0f;
    const float A   = isU ?  2.0f :  1.0f;
    const float B   = isU ? -1.0f :  0.0f;

    float h0=0,h1=0,h2=0,h3=0,h4=0,h5=0,h6=0,h7=0, cxl=0, nhx=0;

    for (int t = 0; t < SEQ; ++t) {
        const float4* xr4 = reinterpret_cast<const float4*>(x + ((long)t * NBATCH + row) * INDIM);
        float acc = bias;
#pragma unroll
        for (int k4 = 0; k4 < 16; ++k4) {
            const float4 v = xr4[k4];
            acc = fmaf(v.x, wx[4*k4+0], acc);
            acc = fmaf(v.y, wx[4*k4+1], acc);
            acc = fmaf(v.z, wx[4*k4+2], acc);
            acc = fmaf(v.w, wx[4*k4+3], acc);
        }
        float ang = acc;
        ang += fmaf(h0, wh0, fmaf(h1, wh1, fmaf(h2, wh2, h3 * wh3)))
             + fmaf(h4, wh4, fmaf(h5, wh5, fmaf(h6, wh6, h7 * wh7)));

        const float c = fast_cos(ang);
        const float cb0 = SWZ(c, 0x018); const float cb1 = SWZ(c, 0x038);
        const float cb2 = SWZ(c, 0x058); const float cb3 = SWZ(c, 0x078);
        const float cb4 = SWZ(c, 0x098); const float cb5 = SWZ(c, 0x0B8);
        const float cb6 = SWZ(c, 0x0D8); const float cb7 = SWZ(c, 0x0F8);

        const float p0 = (mask & 0x01u) ? cb0 : 1.0f;
        const float p1 = (mask & 0x02u) ? cb1 : 1.0f;
        const float p2 = (mask & 0x04u) ? cb2 : 1.0f;
        const float p3 = (mask & 0x08u) ? cb3 : 1.0f;
        const float p4 = (mask & 0x10u) ? cb4 : 1.0f;
        const float p5 = (mask & 0x20u) ? cb5 : 1.0f;
        const float p6 = (mask & 0x40u) ? cb6 : 1.0f;
        const float p7 = (mask & 0x80u) ? cb7 : 1.0f;
        const float z = ((p0*p1)*(p2*p3)) * ((p4*p5)*(p6*p7));

        const float e   = __expf(z * ZL);
        const float act = fmaf(A, __builtin_amdgcn_rcpf(1.0f + e), B);

        const float fg = SWZ(act, 0x007);
        const float ig = SWZ(act, 0x107);
        const float ug = SWZ(act, 0x207);
        const float og = SWZ(act, 0x307);

        const float ncx = fmaf(fg, cxl, ig * ug);
        const float et  = __expf(-2.0f * ncx);
        const float tc  = fmaf(2.0f, __builtin_amdgcn_rcpf(1.0f + et), -1.0f);
        nhx = og * tc;
        cxl = ncx;

        if (lane < 8) out[((long)t * NBATCH + row) * 8 + lane] = nhx;

        h0 = SWZ(nhx, 0x000); h1 = SWZ(nhx, 0x020);
        h2 = SWZ(nhx, 0x040); h3 = SWZ(nhx, 0x060);
        h4 = SWZ(nhx, 0x080); h5 = SWZ(nhx, 0x0A0);
        h6 = SWZ(nhx, 0x0C0); h7 = SWZ(nhx, 0x0E0);
    }

    if (lane < 8) {
        out[OUT_HX + (long)row * 8 + lane] = nhx;
        out[OUT_CX + (long)row * 8 + lane] = cxl;
    }
}

// ---------------------------------------------------------------------------
extern "C" void kernel_launch(void* const* d_in, const int* in_sizes, int n_in,
                              void* d_out, int out_size, void* d_ws, size_t ws_size,
                              hipStream_t stream)
{
    const float* x = (const float*)d_in[0];

    const float *Wf, *bf, *thf, *Wi, *bi, *thi, *Wu, *bu, *thu, *Wo, *bo, *tho;
    if (in_sizes[3] == 8) {  // dict order: W_f,b_f,th_f, W_i,b_i,th_i, ...
        Wf = (const float*)d_in[1];  bf = (const float*)d_in[2];  thf = (const float*)d_in[3];
        Wi = (const float*)d_in[4];  bi = (const float*)d_in[5];  thi = (const float*)d_in[6];
        Wu = (const float*)d_in[7];  bu = (const float*)d_in[8];  thu = (const float*)d_in[9];
        Wo = (const float*)d_in[10]; bo = (const float*)d_in[11]; tho = (const float*)d_in[12];
    } else {                 // signature order
        Wf = (const float*)d_in[1];  bf = (const float*)d_in[2];
        Wi = (const float*)d_in[3];  bi = (const float*)d_in[4];
        Wu = (const float*)d_in[5];  bu = (const float*)d_in[6];
        Wo = (const float*)d_in[7];  bo = (const float*)d_in[8];
        thf = (const float*)d_in[9]; thi = (const float*)d_in[10];
        thu = (const float*)d_in[11]; tho = (const float*)d_in[12];
    }

    float* out = (float*)d_out;
    float* xp  = (float*)d_ws;
    const size_t need = (size_t)SEQ * NBATCH * 32 * sizeof(float);  // 8.4 MB

    if (ws_size >= need) {
        xproj_kernel<<<(SEQ * NBATCH) / 128, 256, 0, stream>>>(
            x, Wf, bf, thf, Wi, bi, thi, Wu, bu, thu, Wo, bo, tho, xp);
        qlstm_scan_kernel<<<NBATCH / 16, 256, 0, stream>>>(
            xp, Wf, Wi, Wu, Wo, out);
    } else {
        qlstm_scan_fused<<<NBATCH / 8, 256, 0, stream>>>(
            x, Wf, bf, thf, Wi, bi, thi, Wu, bu, thu, Wo, bo, tho, out);
    }
}